// Round 1
// baseline (1441.843 us; speedup 1.0000x reference)
//
#include <hip/hip_runtime.h>
#include <hip/hip_bf16.h>

#define N_NODES 20000
#define T_STEPS 8
#define E_EDGES 320000
#define EN_EDGES (E_EDGES + N_NODES)   // edges + self loops = 340000
#define HID 128
#define BN 32                          // nodes per block in gru kernel

__device__ __forceinline__ float sigmoidf_(float z) {
    return 1.0f / (1.0f + expf(-z));
}

// ---------------------------------------------------------------------------
// Detect whether edge_index was staged as int64 (jnp default) or int32.
// int64 little-endian nonneg values < 2^31 look like [v,0,v,0,...] as dwords.
// ---------------------------------------------------------------------------
__global__ void detect_kernel(const unsigned int* __restrict__ ei32,
                              int* __restrict__ flag) {
    int all_zero = 1;
    for (int i = 0; i < 64; ++i) {
        if (ei32[2 * i + 1] != 0u) { all_zero = 0; break; }
    }
    *flag = all_zero;   // 1 => int64 layout
}

// ---------------------------------------------------------------------------
// Edge pass: for each edge (incl. self loops) compute per-head attention
// logit e_h, then atomically accumulate exp(e) and exp(e)*x_src into nd.
// nd layout per node: [den_h0, den_h1, num_h0, num_h1]
// ---------------------------------------------------------------------------
__global__ __launch_bounds__(256) void edge_kernel(
    const void* __restrict__ ei, const int* __restrict__ flag,
    const float* __restrict__ x, int t,
    const float* __restrict__ W_l, const float* __restrict__ b_l,
    const float* __restrict__ W_r, const float* __restrict__ b_r,
    const float* __restrict__ att,
    float* __restrict__ nd)
{
    __shared__ float4 swl[32], swr[32], sbs[32], sat[32];
    const int tid = threadIdx.x;
    if (tid < 128) {
        ((float*)swl)[tid] = W_l[tid];
        ((float*)swr)[tid] = W_r[tid];
        ((float*)sbs)[tid] = b_l[tid] + b_r[tid];
        ((float*)sat)[tid] = att[tid];
    }
    __syncthreads();

    const int e = blockIdx.x * 256 + tid;
    if (e >= EN_EDGES) return;

    int src, dst;
    if (*flag) {
        const long long* e64 = (const long long*)ei;
        if (e < E_EDGES) {
            src = (int)e64[e];
            dst = (int)e64[E_EDGES + e];
        } else {
            src = dst = e - E_EDGES;
        }
    } else {
        const int* e32 = (const int*)ei;
        if (e < E_EDGES) {
            src = e32[e];
            dst = e32[E_EDGES + e];
        } else {
            src = dst = e - E_EDGES;
        }
    }

    const float xs = x[src * T_STEPS + t];
    const float xd = x[dst * T_STEPS + t];

    float e0 = 0.f, e1 = 0.f;
    #pragma unroll
    for (int q = 0; q < 16; ++q) {       // head 0: c = 0..63
        float4 wl = swl[q], wr = swr[q], bs = sbs[q], at = sat[q];
        float a;
        a = xs * wl.x + xd * wr.x + bs.x; e0 += fmaxf(a, 0.2f * a) * at.x;
        a = xs * wl.y + xd * wr.y + bs.y; e0 += fmaxf(a, 0.2f * a) * at.y;
        a = xs * wl.z + xd * wr.z + bs.z; e0 += fmaxf(a, 0.2f * a) * at.z;
        a = xs * wl.w + xd * wr.w + bs.w; e0 += fmaxf(a, 0.2f * a) * at.w;
    }
    #pragma unroll
    for (int q = 16; q < 32; ++q) {      // head 1: c = 64..127
        float4 wl = swl[q], wr = swr[q], bs = sbs[q], at = sat[q];
        float a;
        a = xs * wl.x + xd * wr.x + bs.x; e1 += fmaxf(a, 0.2f * a) * at.x;
        a = xs * wl.y + xd * wr.y + bs.y; e1 += fmaxf(a, 0.2f * a) * at.y;
        a = xs * wl.z + xd * wr.z + bs.z; e1 += fmaxf(a, 0.2f * a) * at.z;
        a = xs * wl.w + xd * wr.w + bs.w; e1 += fmaxf(a, 0.2f * a) * at.w;
    }

    const float ex0 = expf(e0);
    const float ex1 = expf(e1);
    atomicAdd(&nd[dst * 4 + 0], ex0);
    atomicAdd(&nd[dst * 4 + 1], ex1);
    atomicAdd(&nd[dst * 4 + 2], ex0 * xs);
    atomicAdd(&nd[dst * 4 + 3], ex1 * xs);
}

// ---------------------------------------------------------------------------
// Node pass: f = sigmoid(S*wl + sumA*bl + conv_bias); then GRU update.
// Block handles BN=32 nodes. feat = [f, h] staged in LDS.
// GEMM1: ru = sigmoid(feat @ W1 + b1)  (256 cols)
// GEMM2: c  = tanh([f, r*h] @ W2 + b2) (128 cols)
// h_new = u*h + (1-u)*c, in place in h (= d_out).
// Also zeroes this block's nd slots for the next step.
// ---------------------------------------------------------------------------
__global__ __launch_bounds__(256) void gru_kernel(
    float* __restrict__ nd,
    const float* __restrict__ W_l, const float* __restrict__ b_l,
    const float* __restrict__ conv_bias,
    const float* __restrict__ W1, const float* __restrict__ b1,
    const float* __restrict__ W2, const float* __restrict__ b2,
    float* __restrict__ h)
{
    __shared__ float feat[BN][256];
    __shared__ float ubuf[BN][128];
    __shared__ float A[BN][4];

    const int t  = threadIdx.x;
    const int n0 = blockIdx.x * BN;

    // stage numer/denom, zero for next step (same thread -> no hazard)
    if (t < BN * 4) {
        A[t >> 2][t & 3] = nd[n0 * 4 + t];
        nd[n0 * 4 + t] = 0.f;
    }
    __syncthreads();

    // phase 0: build feat = [f | h]
    if (t < 128) {
        const int head = t >> 6;
        const float wl = W_l[t], bl = b_l[t], cb = conv_bias[t];
        for (int n = 0; n < BN; ++n) {
            const float den = A[n][head];
            const float num = A[n][2 + head];
            const float inv = 1.0f / (den + 1e-16f);
            const float z = num * inv * wl + den * inv * bl + cb;
            feat[n][t] = sigmoidf_(z);
        }
    } else {
        const int ch = t - 128;
        for (int n = 0; n < BN; ++n) {
            feat[n][128 + ch] = h[(size_t)(n0 + n) * HID + ch];
        }
    }
    __syncthreads();

    // phase 1: GEMM1 -> ru. thread covers cols (jj, jj+1) for 16 nodes.
    const int jj = (t & 127) * 2;
    const int nh = t >> 7;   // node half: 0 or 1
    float acc0[16], acc1[16];
    {
        const float bb0 = b1[jj], bb1 = b1[jj + 1];
        #pragma unroll
        for (int i = 0; i < 16; ++i) { acc0[i] = bb0; acc1[i] = bb1; }
    }
    for (int k4 = 0; k4 < 64; ++k4) {
        const float2 w0 = *(const float2*)&W1[(4 * k4 + 0) * 256 + jj];
        const float2 w1 = *(const float2*)&W1[(4 * k4 + 1) * 256 + jj];
        const float2 w2 = *(const float2*)&W1[(4 * k4 + 2) * 256 + jj];
        const float2 w3 = *(const float2*)&W1[(4 * k4 + 3) * 256 + jj];
        #pragma unroll
        for (int i = 0; i < 16; ++i) {
            const float4 f = *(const float4*)&feat[nh * 16 + i][4 * k4];
            acc0[i] += f.x * w0.x + f.y * w1.x + f.z * w2.x + f.w * w3.x;
            acc1[i] += f.x * w0.y + f.y * w1.y + f.z * w2.y + f.w * w3.y;
        }
    }
    __syncthreads();   // all GEMM1 LDS reads complete before feat overwrite

    if (jj < 128) {    // r columns: overwrite h slot with r*h
        #pragma unroll
        for (int i = 0; i < 16; ++i) {
            const int n = nh * 16 + i;
            const float r0 = sigmoidf_(acc0[i]);
            const float r1 = sigmoidf_(acc1[i]);
            const float h0v = feat[n][128 + jj];
            const float h1v = feat[n][128 + jj + 1];
            feat[n][128 + jj]     = r0 * h0v;
            feat[n][128 + jj + 1] = r1 * h1v;
        }
    } else {           // u columns: store to ubuf
        const int uc = jj - 128;
        #pragma unroll
        for (int i = 0; i < 16; ++i) {
            const int n = nh * 16 + i;
            ubuf[n][uc]     = sigmoidf_(acc0[i]);
            ubuf[n][uc + 1] = sigmoidf_(acc1[i]);
        }
    }
    __syncthreads();

    // phase 2: GEMM2 -> c; h_new. thread covers cols (j2, j2+1) for 8 nodes.
    const int j2  = (t & 63) * 2;
    const int nh2 = t >> 6;   // 0..3
    float c0[8], c1[8];
    {
        const float bb0 = b2[j2], bb1 = b2[j2 + 1];
        #pragma unroll
        for (int i = 0; i < 8; ++i) { c0[i] = bb0; c1[i] = bb1; }
    }
    for (int k4 = 0; k4 < 64; ++k4) {
        const float2 w0 = *(const float2*)&W2[(4 * k4 + 0) * 128 + j2];
        const float2 w1 = *(const float2*)&W2[(4 * k4 + 1) * 128 + j2];
        const float2 w2 = *(const float2*)&W2[(4 * k4 + 2) * 128 + j2];
        const float2 w3 = *(const float2*)&W2[(4 * k4 + 3) * 128 + j2];
        #pragma unroll
        for (int i = 0; i < 8; ++i) {
            const float4 f = *(const float4*)&feat[nh2 * 8 + i][4 * k4];
            c0[i] += f.x * w0.x + f.y * w1.x + f.z * w2.x + f.w * w3.x;
            c1[i] += f.x * w0.y + f.y * w1.y + f.z * w2.y + f.w * w3.y;
        }
    }
    #pragma unroll
    for (int i = 0; i < 8; ++i) {
        const int n = nh2 * 8 + i;
        const float cc0 = tanhf(c0[i]);
        const float cc1 = tanhf(c1[i]);
        const float u0 = ubuf[n][j2];
        const float u1 = ubuf[n][j2 + 1];
        float* hp = &h[(size_t)(n0 + n) * HID + j2];
        const float2 hv = *(const float2*)hp;
        float2 hn;
        hn.x = u0 * hv.x + (1.0f - u0) * cc0;
        hn.y = u1 * hv.y + (1.0f - u1) * cc1;
        *(float2*)hp = hn;
    }
}

// ---------------------------------------------------------------------------
extern "C" void kernel_launch(void* const* d_in, const int* in_sizes, int n_in,
                              void* d_out, int out_size, void* d_ws, size_t ws_size,
                              hipStream_t stream) {
    const float* x   = (const float*)d_in[0];
    const void*  ei  = d_in[1];
    // d_in[2] edge_weight: unused by the reference
    const float* W_l = (const float*)d_in[3];
    const float* b_l = (const float*)d_in[4];
    const float* W_r = (const float*)d_in[5];
    const float* b_r = (const float*)d_in[6];
    const float* att = (const float*)d_in[7];
    const float* cb  = (const float*)d_in[8];
    const float* W1  = (const float*)d_in[9];
    const float* b1  = (const float*)d_in[10];
    const float* W2  = (const float*)d_in[11];
    const float* b2  = (const float*)d_in[12];

    float* h    = (float*)d_out;          // hidden state lives in d_out
    char*  ws   = (char*)d_ws;
    int*   flag = (int*)ws;
    float* nd   = (float*)(ws + 256);     // N*4 floats

    detect_kernel<<<1, 1, 0, stream>>>((const unsigned int*)ei, flag);
    hipMemsetAsync(nd, 0, (size_t)N_NODES * 4 * sizeof(float), stream);
    hipMemsetAsync(h, 0, (size_t)N_NODES * HID * sizeof(float), stream);

    const int edge_blocks = (EN_EDGES + 255) / 256;
    const int gru_blocks  = N_NODES / BN;
    for (int t = 0; t < T_STEPS; ++t) {
        edge_kernel<<<edge_blocks, 256, 0, stream>>>(
            ei, flag, x, t, W_l, b_l, W_r, b_r, att, nd);
        gru_kernel<<<gru_blocks, 256, 0, stream>>>(
            nd, W_l, b_l, cb, W1, b1, W2, b2, h);
    }
}

// Round 3
// 865.798 us; speedup vs baseline: 1.6653x; 1.6653x over previous
//
#include <hip/hip_runtime.h>
#include <hip/hip_bf16.h>

#define N_NODES 20000
#define T_STEPS 8
#define E_EDGES 320000
#define EN_EDGES (E_EDGES + N_NODES)   // edges + self loops = 340000
#define HID 128
#define BN 80                          // nodes per block: 20000/80 = 250 blocks exactly

typedef short short8 __attribute__((ext_vector_type(8)));
typedef float f32x4 __attribute__((ext_vector_type(4)));

// ---- all scratch in device globals: independent of ws_size ---------------
__device__ __attribute__((aligned(16))) float g_nd[N_NODES * 4];
__device__ __attribute__((aligned(16))) short g_w1hi[65536];
__device__ __attribute__((aligned(16))) short g_w1lo[65536];
__device__ __attribute__((aligned(16))) short g_w2hi[32768];
__device__ __attribute__((aligned(16))) short g_w2lo[32768];
__device__ int g_flag;

__device__ __forceinline__ float sigmoidf_(float z) {
    return 1.0f / (1.0f + expf(-z));
}
__device__ __forceinline__ unsigned short f2bf(float f) {
    unsigned u = __builtin_bit_cast(unsigned, f);
    unsigned r = (u + 0x7FFFu + ((u >> 16) & 1u)) >> 16;   // RTNE
    return (unsigned short)r;
}
__device__ __forceinline__ float bf2f(unsigned short s) {
    return __builtin_bit_cast(float, ((unsigned)s) << 16);
}

// ---------------------------------------------------------------------------
// init: zero g_nd; thread 0 also detects int64-vs-int32 edge_index layout.
// ---------------------------------------------------------------------------
__global__ __launch_bounds__(256) void init_kernel(const unsigned int* __restrict__ ei32) {
    const int i = blockIdx.x * 256 + threadIdx.x;
    if (i < N_NODES * 4) g_nd[i] = 0.f;
    if (i == 0) {
        int all_zero = 1;
        for (int k = 0; k < 64; ++k) {
            if (ei32[2 * k + 1] != 0u) { all_zero = 0; break; }
        }
        g_flag = all_zero;   // 1 => int64 layout
    }
}

// ---------------------------------------------------------------------------
// Prep: build fragment-packed, transposed bf16 hi/lo copies of W1, W2.
// Layout: idx = ((kb*NCOLS + n)*4 + kq)*8 + r  holds  W[kb*32+kq*8+r][n]
// so a wave's B-fragment load (col=lane&15, kq=lane>>4) is a contiguous 1KB.
// ---------------------------------------------------------------------------
__global__ __launch_bounds__(256) void prep_kernel(
    const float* __restrict__ W1, const float* __restrict__ W2)
{
    int i = blockIdx.x * 256 + threadIdx.x;   // 0 .. 98303
    if (i < 65536) {                          // W1: (256,256) row-major [k][n]
        int k = i >> 8, n = i & 255;
        float w = W1[i];
        int kb = k >> 5, kq = (k >> 3) & 3, r = k & 7;
        int idx = ((kb * 256 + n) * 4 + kq) * 8 + r;
        unsigned short hi = f2bf(w);
        float lo = w - bf2f(hi);
        g_w1hi[idx] = (short)hi;
        g_w1lo[idx] = (short)f2bf(lo);
    } else {                                  // W2: (256,128) row-major [k][n]
        int j = i - 65536;
        int k = j >> 7, n = j & 127;
        float w = W2[j];
        int kb = k >> 5, kq = (k >> 3) & 3, r = k & 7;
        int idx = ((kb * 128 + n) * 4 + kq) * 8 + r;
        unsigned short hi = f2bf(w);
        float lo = w - bf2f(hi);
        g_w2hi[idx] = (short)hi;
        g_w2lo[idx] = (short)f2bf(lo);
    }
}

// ---------------------------------------------------------------------------
// Edge pass: per-edge attention logits -> exp -> 4 float atomics per edge
// into g_nd[node] = [den0, den1, num0, num1].
// ---------------------------------------------------------------------------
__global__ __launch_bounds__(256) void edge_kernel(
    const void* __restrict__ ei,
    const float* __restrict__ x, int t,
    const float* __restrict__ W_l, const float* __restrict__ b_l,
    const float* __restrict__ W_r, const float* __restrict__ b_r,
    const float* __restrict__ att)
{
    __shared__ float4 swl[32], swr[32], sbs[32], sat[32];
    const int tid = threadIdx.x;
    if (tid < 128) {
        ((float*)swl)[tid] = W_l[tid];
        ((float*)swr)[tid] = W_r[tid];
        ((float*)sbs)[tid] = b_l[tid] + b_r[tid];
        ((float*)sat)[tid] = att[tid];
    }
    __syncthreads();

    const int e = blockIdx.x * 256 + tid;
    if (e >= EN_EDGES) return;

    int src, dst;
    if (g_flag) {
        const long long* e64 = (const long long*)ei;
        if (e < E_EDGES) { src = (int)e64[e]; dst = (int)e64[E_EDGES + e]; }
        else             { src = dst = e - E_EDGES; }
    } else {
        const int* e32 = (const int*)ei;
        if (e < E_EDGES) { src = e32[e]; dst = e32[E_EDGES + e]; }
        else             { src = dst = e - E_EDGES; }
    }

    const float xs = x[src * T_STEPS + t];
    const float xd = x[dst * T_STEPS + t];

    float e0 = 0.f, e1 = 0.f;
    #pragma unroll
    for (int q = 0; q < 16; ++q) {
        float4 wl = swl[q], wr = swr[q], bs = sbs[q], at = sat[q];
        float a;
        a = xs * wl.x + xd * wr.x + bs.x; e0 += fmaxf(a, 0.2f * a) * at.x;
        a = xs * wl.y + xd * wr.y + bs.y; e0 += fmaxf(a, 0.2f * a) * at.y;
        a = xs * wl.z + xd * wr.z + bs.z; e0 += fmaxf(a, 0.2f * a) * at.z;
        a = xs * wl.w + xd * wr.w + bs.w; e0 += fmaxf(a, 0.2f * a) * at.w;
    }
    #pragma unroll
    for (int q = 16; q < 32; ++q) {
        float4 wl = swl[q], wr = swr[q], bs = sbs[q], at = sat[q];
        float a;
        a = xs * wl.x + xd * wr.x + bs.x; e1 += fmaxf(a, 0.2f * a) * at.x;
        a = xs * wl.y + xd * wr.y + bs.y; e1 += fmaxf(a, 0.2f * a) * at.y;
        a = xs * wl.z + xd * wr.z + bs.z; e1 += fmaxf(a, 0.2f * a) * at.z;
        a = xs * wl.w + xd * wr.w + bs.w; e1 += fmaxf(a, 0.2f * a) * at.w;
    }

    const float ex0 = expf(e0);
    const float ex1 = expf(e1);
    atomicAdd(&g_nd[dst * 4 + 0], ex0);
    atomicAdd(&g_nd[dst * 4 + 1], ex1);
    atomicAdd(&g_nd[dst * 4 + 2], ex0 * xs);
    atomicAdd(&g_nd[dst * 4 + 3], ex1 * xs);
}

// ---------------------------------------------------------------------------
// GRU via MFMA. 80 nodes/block, 512 threads (8 waves).
// feat [80][256] bf16 LDS, XOR-granule swizzle: granule g' = g ^ (row&7).
// GEMM1: z=[f,h]@(W1hi+W1lo)+b1 -> r (cols<128) overwrites h-region as r*h;
//        u (cols>=128) -> ubuf. GEMM2: c=tanh([f,r*h]@(W2hi+W2lo)+b2);
// h_new = u*h + (1-u)*c, in place in h. Also zeroes g_nd for next step.
// ---------------------------------------------------------------------------
__global__ __launch_bounds__(512) void gru_mfma_kernel(
    const float* __restrict__ W_l, const float* __restrict__ b_l,
    const float* __restrict__ conv_bias,
    const float* __restrict__ b1, const float* __restrict__ b2,
    float* __restrict__ h)
{
    __shared__ short featA[BN * 256];   // 40960 B
    __shared__ short ubuf[BN * 128];    // 20480 B
    __shared__ float sA[BN][4];         // 1280 B
    __shared__ float swl[128], sbl[128], scb[128];   // 1536 B

    const int t   = threadIdx.x;
    const int n0g = blockIdx.x * BN;

    if (t < 128) { swl[t] = W_l[t]; sbl[t] = b_l[t]; scb[t] = conv_bias[t]; }
    if (t < BN * 4) {
        const int gi = n0g * 4 + t;
        sA[t >> 2][t & 3] = g_nd[gi];
        g_nd[gi] = 0.f;
    }
    __syncthreads();

    // phase 0: build feat = [f | h] in swizzled bf16 LDS. 2560 granules of 8.
    #pragma unroll
    for (int it = 0; it < 5; ++it) {
        const int G    = t + it * 512;
        const int node = G >> 5;
        const int g    = G & 31;
        short8 v;
        if (g < 16) {                       // f region, channels g*8..g*8+7
            const int head = g >> 3;
            const float den = sA[node][head];
            const float num = sA[node][2 + head];
            const float inv = 1.0f / (den + 1e-16f);
            #pragma unroll
            for (int r = 0; r < 8; ++r) {
                const int c = g * 8 + r;
                const float z = (num * swl[c] + den * sbl[c]) * inv + scb[c];
                v[r] = (short)f2bf(sigmoidf_(z));
            }
        } else {                            // h region
            const int c0 = (g - 16) * 8;
            const float* hp = &h[(size_t)(n0g + node) * HID + c0];
            const float4 h0 = *(const float4*)hp;
            const float4 h1 = *(const float4*)(hp + 4);
            v[0] = (short)f2bf(h0.x); v[1] = (short)f2bf(h0.y);
            v[2] = (short)f2bf(h0.z); v[3] = (short)f2bf(h0.w);
            v[4] = (short)f2bf(h1.x); v[5] = (short)f2bf(h1.y);
            v[6] = (short)f2bf(h1.z); v[7] = (short)f2bf(h1.w);
        }
        const int gsw = g ^ (node & 7);
        *(short8*)&featA[node * 256 + gsw * 8] = v;
    }
    __syncthreads();

    const int wid = t >> 6;
    const int l   = t & 63;
    const int lr  = l & 15;    // A row-in-frag / B,D col
    const int lk  = l >> 4;    // k-group; D row-group

    // ---------------- GEMM1: M=80, N=256 (32/wave), K=256, hi+lo ----------
    f32x4 acc[5][2];
    #pragma unroll
    for (int nf = 0; nf < 2; ++nf) {
        const float bb = b1[wid * 32 + nf * 16 + lr];
        #pragma unroll
        for (int mf = 0; mf < 5; ++mf)
            acc[mf][nf] = (f32x4){bb, bb, bb, bb};
    }
    #pragma unroll
    for (int kb = 0; kb < 8; ++kb) {
        short8 ah[5];
        #pragma unroll
        for (int mf = 0; mf < 5; ++mf) {
            const int row = mf * 16 + lr;
            const int g   = (kb * 4 + lk) ^ (row & 7);
            ah[mf] = *(short8*)&featA[row * 256 + g * 8];
        }
        #pragma unroll
        for (int nf = 0; nf < 2; ++nf) {
            const int ncol = wid * 32 + nf * 16 + lr;
            const int bidx = ((kb * 256 + ncol) * 4 + lk) * 8;
            const short8 bh = *(const short8*)&g_w1hi[bidx];
            const short8 bl = *(const short8*)&g_w1lo[bidx];
            #pragma unroll
            for (int mf = 0; mf < 5; ++mf) {
                acc[mf][nf] = __builtin_amdgcn_mfma_f32_16x16x32_bf16(ah[mf], bh, acc[mf][nf], 0, 0, 0);
                acc[mf][nf] = __builtin_amdgcn_mfma_f32_16x16x32_bf16(ah[mf], bl, acc[mf][nf], 0, 0, 0);
            }
        }
    }
    __syncthreads();   // all GEMM1 A-reads done before feat overwrite

    // epilogue 1: waves 0-3 own r (cols 0..127): feat h-region <- bf16(r*h).
    //             waves 4-7 own u (cols 128..255): ubuf <- bf16(u).
    if (wid < 4) {
        #pragma unroll
        for (int mf = 0; mf < 5; ++mf) {
            #pragma unroll
            for (int nf = 0; nf < 2; ++nf) {
                const int colk = 128 + wid * 32 + nf * 16 + lr;  // k-index of h elem
                #pragma unroll
                for (int j = 0; j < 4; ++j) {
                    const int row = mf * 16 + lk * 4 + j;
                    const float r = sigmoidf_(acc[mf][nf][j]);
                    const int g  = (colk >> 3) ^ (row & 7);
                    const int ad = row * 256 + g * 8 + (colk & 7);
                    const float hv = bf2f((unsigned short)featA[ad]);
                    featA[ad] = (short)f2bf(r * hv);
                }
            }
        }
    } else {
        #pragma unroll
        for (int mf = 0; mf < 5; ++mf) {
            #pragma unroll
            for (int nf = 0; nf < 2; ++nf) {
                const int colu = (wid - 4) * 32 + nf * 16 + lr;
                #pragma unroll
                for (int j = 0; j < 4; ++j) {
                    const int row = mf * 16 + lk * 4 + j;
                    const float u = sigmoidf_(acc[mf][nf][j]);
                    ubuf[row * 128 + colu] = (short)f2bf(u);
                }
            }
        }
    }
    __syncthreads();

    // ---------------- GEMM2: M=80, N=128 (16/wave), K=256, hi+lo ----------
    f32x4 acc2[5];
    {
        const float bb = b2[wid * 16 + lr];
        #pragma unroll
        for (int mf = 0; mf < 5; ++mf)
            acc2[mf] = (f32x4){bb, bb, bb, bb};
    }
    #pragma unroll
    for (int kb = 0; kb < 8; ++kb) {
        short8 ah[5];
        #pragma unroll
        for (int mf = 0; mf < 5; ++mf) {
            const int row = mf * 16 + lr;
            const int g   = (kb * 4 + lk) ^ (row & 7);
            ah[mf] = *(short8*)&featA[row * 256 + g * 8];
        }
        const int ncol = wid * 16 + lr;
        const int bidx = ((kb * 128 + ncol) * 4 + lk) * 8;
        const short8 bh = *(const short8*)&g_w2hi[bidx];
        const short8 bl = *(const short8*)&g_w2lo[bidx];
        #pragma unroll
        for (int mf = 0; mf < 5; ++mf) {
            acc2[mf] = __builtin_amdgcn_mfma_f32_16x16x32_bf16(ah[mf], bh, acc2[mf], 0, 0, 0);
            acc2[mf] = __builtin_amdgcn_mfma_f32_16x16x32_bf16(ah[mf], bl, acc2[mf], 0, 0, 0);
        }
    }

    // epilogue 2: c = tanh(z2); h_new = u*h + (1-u)*c
    #pragma unroll
    for (int mf = 0; mf < 5; ++mf) {
        const int col = wid * 16 + lr;
        #pragma unroll
        for (int j = 0; j < 4; ++j) {
            const int row = mf * 16 + lk * 4 + j;
            const float c = tanhf(acc2[mf][j]);
            const float u = bf2f((unsigned short)ubuf[row * 128 + col]);
            float* hp = &h[(size_t)(n0g + row) * HID + col];
            const float hv = *hp;
            *hp = u * hv + (1.0f - u) * c;
        }
    }
}

// ---------------------------------------------------------------------------
extern "C" void kernel_launch(void* const* d_in, const int* in_sizes, int n_in,
                              void* d_out, int out_size, void* d_ws, size_t ws_size,
                              hipStream_t stream) {
    const float* x   = (const float*)d_in[0];
    const void*  ei  = d_in[1];
    // d_in[2] edge_weight: unused by the reference
    const float* W_l = (const float*)d_in[3];
    const float* b_l = (const float*)d_in[4];
    const float* W_r = (const float*)d_in[5];
    const float* b_r = (const float*)d_in[6];
    const float* att = (const float*)d_in[7];
    const float* cb  = (const float*)d_in[8];
    const float* W1  = (const float*)d_in[9];
    const float* b1  = (const float*)d_in[10];
    const float* W2  = (const float*)d_in[11];
    const float* b2  = (const float*)d_in[12];

    float* h = (float*)d_out;                 // hidden state lives in d_out
    (void)d_ws; (void)ws_size;

    init_kernel<<<(N_NODES * 4 + 255) / 256, 256, 0, stream>>>((const unsigned int*)ei);
    prep_kernel<<<384, 256, 0, stream>>>(W1, W2);
    hipMemsetAsync(h, 0, (size_t)N_NODES * HID * sizeof(float), stream);

    const int edge_blocks = (EN_EDGES + 255) / 256;
    const int gru_blocks  = N_NODES / BN;   // 250
    for (int t = 0; t < T_STEPS; ++t) {
        edge_kernel<<<edge_blocks, 256, 0, stream>>>(
            ei, x, t, W_l, b_l, W_r, b_r, att);
        gru_mfma_kernel<<<gru_blocks, 512, 0, stream>>>(
            W_l, b_l, cb, b1, b2, h);
    }
}

// Round 4
// 327.122 us; speedup vs baseline: 4.4077x; 2.6467x over previous
//
#include <hip/hip_runtime.h>
#include <hip/hip_bf16.h>

#define N_NODES 20000
#define T_STEPS 8
#define E_EDGES 320000
#define HID 128
#define BN 80                          // nodes per gru block: 250 blocks exactly

typedef short short8 __attribute__((ext_vector_type(8)));
typedef float f32x4 __attribute__((ext_vector_type(4)));

// ---- all scratch in device globals: independent of ws_size ----------------
__device__ __attribute__((aligned(16))) float g_xT[T_STEPS * N_NODES];      // 640 KB
__device__ __attribute__((aligned(16))) float g_ndf[T_STEPS * N_NODES * 4]; // 2.56 MB
__device__ __attribute__((aligned(16))) int   g_cnt[N_NODES];
__device__ __attribute__((aligned(16))) int   g_rowptr[N_NODES + 1];
__device__ __attribute__((aligned(16))) int   g_cursor[N_NODES];
__device__ __attribute__((aligned(16))) int   g_sorted[E_EDGES];            // 1.28 MB
__device__ __attribute__((aligned(16))) short g_w1hi[65536];
__device__ __attribute__((aligned(16))) short g_w1lo[65536];
__device__ __attribute__((aligned(16))) short g_w2hi[32768];
__device__ __attribute__((aligned(16))) short g_w2lo[32768];
__device__ float g_lin[6];            // P,Q,R per head
__device__ int   g_flag;

__device__ __forceinline__ float fsig(float z) {
    return 1.0f / (1.0f + __expf(-z));
}
__device__ __forceinline__ unsigned short f2bf(float f) {
    unsigned u = __builtin_bit_cast(unsigned, f);
    unsigned r = (u + 0x7FFFu + ((u >> 16) & 1u)) >> 16;   // RTNE
    return (unsigned short)r;
}
__device__ __forceinline__ float bf2f(unsigned short s) {
    return __builtin_bit_cast(float, ((unsigned)s) << 16);
}

// ---------------------------------------------------------------------------
// init: transpose x -> xT[t][n]; zero histogram; detect int64/int32 staging.
// ---------------------------------------------------------------------------
__global__ __launch_bounds__(256) void init_kernel(
    const float* __restrict__ x, const unsigned int* __restrict__ ei32)
{
    const int i = blockIdx.x * 256 + threadIdx.x;
    if (i < T_STEPS * N_NODES) {
        const int n = i >> 3, t = i & 7;
        g_xT[t * N_NODES + n] = x[i];
    }
    if (i < N_NODES) g_cnt[i] = 0;
    if (i == 0) {
        int all_zero = 1;
        for (int k = 0; k < 64; ++k)
            if (ei32[2 * k + 1] != 0u) { all_zero = 0; break; }
        g_flag = all_zero;   // 1 => int64 layout
    }
}

__device__ __forceinline__ void load_edge(const void* ei, int e, int& src, int& dst) {
    if (g_flag) {
        const long long* p = (const long long*)ei;
        src = (int)p[e]; dst = (int)p[E_EDGES + e];
    } else {
        const int* p = (const int*)ei;
        src = p[e]; dst = p[E_EDGES + e];
    }
}

__global__ __launch_bounds__(256) void hist_kernel(const void* __restrict__ ei) {
    const int e = blockIdx.x * 256 + threadIdx.x;
    if (e >= E_EDGES) return;
    int src, dst; load_edge(ei, e, src, dst);
    atomicAdd(&g_cnt[dst], 1);
}

// single block, 1024 threads: exclusive scan of g_cnt -> g_rowptr, g_cursor
__global__ __launch_bounds__(1024) void scan_kernel() {
    __shared__ int part[1024];
    const int tid  = threadIdx.x;
    const int base = tid * 20;
    int local[20];
    int s = 0;
    #pragma unroll
    for (int i = 0; i < 20; ++i) {
        const int n = base + i;
        const int c = (n < N_NODES) ? g_cnt[n] : 0;
        local[i] = s; s += c;
    }
    part[tid] = s;
    __syncthreads();
    for (int off = 1; off < 1024; off <<= 1) {
        const int v = (tid >= off) ? part[tid - off] : 0;
        __syncthreads();
        part[tid] += v;
        __syncthreads();
    }
    const int pre = (tid == 0) ? 0 : part[tid - 1];
    #pragma unroll
    for (int i = 0; i < 20; ++i) {
        const int n = base + i;
        if (n < N_NODES) {
            const int v = pre + local[i];
            g_rowptr[n] = v;
            g_cursor[n] = v;
        }
    }
    if (tid == 1023) g_rowptr[N_NODES] = part[1023];
}

__global__ __launch_bounds__(256) void scatter_kernel(const void* __restrict__ ei) {
    const int e = blockIdx.x * 256 + threadIdx.x;
    if (e >= E_EDGES) return;
    int src, dst; load_edge(ei, e, src, dst);
    const int pos = atomicAdd(&g_cursor[dst], 1);
    g_sorted[pos] = src;
}

// ---------------------------------------------------------------------------
// Prep: pack transposed bf16 hi/lo W1,W2 fragments; compute P,Q,R per head.
// ---------------------------------------------------------------------------
__global__ __launch_bounds__(256) void prep_kernel(
    const float* __restrict__ W1, const float* __restrict__ W2,
    const float* __restrict__ W_l, const float* __restrict__ b_l,
    const float* __restrict__ W_r, const float* __restrict__ b_r,
    const float* __restrict__ att)
{
    int i = blockIdx.x * 256 + threadIdx.x;   // 0 .. 98303
    if (i < 65536) {                          // W1: (256,256) [k][n]
        int k = i >> 8, n = i & 255;
        float w = W1[i];
        int kb = k >> 5, kq = (k >> 3) & 3, r = k & 7;
        int idx = ((kb * 256 + n) * 4 + kq) * 8 + r;
        unsigned short hi = f2bf(w);
        g_w1hi[idx] = (short)hi;
        g_w1lo[idx] = (short)f2bf(w - bf2f(hi));
    } else {                                  // W2: (256,128) [k][n]
        int j = i - 65536;
        int k = j >> 7, n = j & 127;
        float w = W2[j];
        int kb = k >> 5, kq = (k >> 3) & 3, r = k & 7;
        int idx = ((kb * 128 + n) * 4 + kq) * 8 + r;
        unsigned short hi = f2bf(w);
        g_w2hi[idx] = (short)hi;
        g_w2lo[idx] = (short)f2bf(w - bf2f(hi));
    }
    if (blockIdx.x == 0 && threadIdx.x < 2) {
        const int hh = threadIdx.x;
        float P = 0.f, Q = 0.f, R = 0.f;
        for (int k = 0; k < 64; ++k) {
            const int c = hh * 64 + k;
            const float a = att[c];
            P = fmaf(a, W_l[c], P);
            Q = fmaf(a, W_r[c], Q);
            R = fmaf(a, b_l[c] + b_r[c], R);
        }
        g_lin[hh * 3 + 0] = P;
        g_lin[hh * 3 + 1] = Q;
        g_lin[hh * 3 + 2] = R;
    }
}

// ---------------------------------------------------------------------------
// Edge pass, all 8 timesteps, no atomics. Lane = (node, head); block covers
// 128 nodes x 2 heads; blockIdx.y = t. Per in-edge (+self loop):
//   e = 0.6*(xs*P + xd*Q + R) + 0.4*sum_c at_c*|xs*wl_c + xd*wr_c + bs_c|
// den += exp(e); num += exp(e)*xs.  Edges chunked 8-wide for load ILP and
// LDS-read amortization.
// ---------------------------------------------------------------------------
__global__ __launch_bounds__(256) void edge_all_kernel(
    const float* __restrict__ W_l, const float* __restrict__ b_l,
    const float* __restrict__ W_r, const float* __restrict__ b_r,
    const float* __restrict__ att)
{
    __shared__ float4 ch4[128];
    const int tid = threadIdx.x;
    if (tid < 128)
        ch4[tid] = make_float4(W_l[tid], W_r[tid], b_l[tid] + b_r[tid], att[tid]);
    __syncthreads();

    const int n    = blockIdx.x * 128 + (tid >> 1);
    const int head = tid & 1;
    const int t    = blockIdx.y;
    if (n >= N_NODES) return;

    const float* xrow = &g_xT[t * N_NODES];
    const float xd = xrow[n];
    const float P = g_lin[head * 3 + 0];
    const float Q = g_lin[head * 3 + 1];
    const float R = g_lin[head * 3 + 2];
    const float4* chh = &ch4[head * 64];

    const int base = g_rowptr[n];
    const int deg  = g_rowptr[n + 1] - base;
    const int tot  = deg + 1;            // +1 = self loop at idx 0

    float den = 0.f, num = 0.f;
    for (int cs = 0; cs < tot; cs += 8) {
        int m = tot - cs; if (m > 8) m = 8;
        float xs[8];
        #pragma unroll
        for (int e = 0; e < 8; ++e) {
            xs[e] = 0.f;
            if (e < m) {
                const int idx = cs + e;
                xs[e] = (idx == 0) ? xd : xrow[g_sorted[base + idx - 1]];
            }
        }
        float ea[8];
        #pragma unroll
        for (int e = 0; e < 8; ++e) ea[e] = 0.f;
        #pragma unroll 4
        for (int c = 0; c < 64; ++c) {
            const float4 f = chh[c];
            const float dpart = fmaf(xd, f.y, f.z);
            #pragma unroll
            for (int e = 0; e < 8; ++e) {
                const float a = fmaf(xs[e], f.x, dpart);
                ea[e] = fmaf(fabsf(a), f.w, ea[e]);
            }
        }
        #pragma unroll
        for (int e = 0; e < 8; ++e) {
            if (e < m) {
                const float ee = fmaf(0.6f, fmaf(xs[e], P, fmaf(xd, Q, R)), 0.4f * ea[e]);
                const float ex = __expf(ee);
                den += ex;
                num = fmaf(ex, xs[e], num);
            }
        }
    }
    g_ndf[((size_t)t * N_NODES + n) * 4 + head]     = den;
    g_ndf[((size_t)t * N_NODES + n) * 4 + 2 + head] = num;
}

// ---------------------------------------------------------------------------
// Full 8-step GRU in one kernel. 80 nodes/block, 512 threads (8 waves).
// featA [80][256] bf16 (XOR-granule swizzle g'=g^(node&7)); hbuf fp32 carry.
// GEMM1 col pairing: wave w owns r-cols [16w,16w+16) (nf=0) and u-cols
// [128+16w, ...) (nf=1)  ->  u*h and u stay in registers through GEMM2.
// ---------------------------------------------------------------------------
__global__ __launch_bounds__(512) void gru_all_kernel(
    const float* __restrict__ W_l, const float* __restrict__ b_l,
    const float* __restrict__ conv_bias,
    const float* __restrict__ b1, const float* __restrict__ b2,
    float* __restrict__ hout)
{
    __shared__ short featA[BN * 256];   // 40960 B
    __shared__ float hbuf[BN * HID];    // 40960 B
    __shared__ float swl[128], sbl[128], scb[128], sb1a[128], sb1b[128], sb2[128];

    const int t   = threadIdx.x;
    const int n0g = blockIdx.x * BN;

    if (t < 128) {
        swl[t] = W_l[t]; sbl[t] = b_l[t]; scb[t] = conv_bias[t];
        sb1a[t] = b1[t]; sb1b[t] = b1[128 + t]; sb2[t] = b2[t];
    }
    // zero the h carry (fp32) and featA h-region (bf16)
    for (int i = t; i < BN * HID; i += 512) hbuf[i] = 0.f;
    for (int i = t; i < BN * 16; i += 512) {
        const int node = i >> 4;
        const int g    = 16 + (i & 15);
        const int gsw  = g ^ (node & 7);
        *(short8*)&featA[node * 256 + gsw * 8] = (short8)0;
    }

    const int wid = t >> 6;
    const int l   = t & 63;
    const int lr  = l & 15;
    const int lk  = l >> 4;
    const int ec  = wid * 16 + lr;      // this wave's channel/column set

    f32x4 uh[5], us[5];

    for (int step = 0; step < T_STEPS; ++step) {
        // ---- phase 0: f -> featA f-region (1280 granule tasks) -----------
        for (int G = t; G < BN * 16; G += 512) {
            const int node = G >> 4;
            const int g    = G & 15;
            const int head = g >> 3;
            const size_t bi = ((size_t)step * N_NODES + n0g + node) * 4;
            const float den = g_ndf[bi + head];
            const float num = g_ndf[bi + 2 + head];
            const float inv = 1.0f / (den + 1e-16f);
            short8 v;
            #pragma unroll
            for (int r = 0; r < 8; ++r) {
                const int c = g * 8 + r;
                const float z = (num * swl[c] + den * sbl[c]) * inv + scb[c];
                v[r] = (short)f2bf(fsig(z));
            }
            const int gsw = g ^ (node & 7);
            *(short8*)&featA[node * 256 + gsw * 8] = v;
        }
        __syncthreads();

        // ---- GEMM1: M=80, K=256; this wave: cols ec (r) and 128+ec (u) ---
        f32x4 acc[5][2];
        {
            const float ba = sb1a[ec], bb = sb1b[ec];
            #pragma unroll
            for (int mf = 0; mf < 5; ++mf) {
                acc[mf][0] = (f32x4){ba, ba, ba, ba};
                acc[mf][1] = (f32x4){bb, bb, bb, bb};
            }
        }
        #pragma unroll
        for (int kb = 0; kb < 8; ++kb) {
            short8 ah[5];
            #pragma unroll
            for (int mf = 0; mf < 5; ++mf) {
                const int row = mf * 16 + lr;
                const int g   = (kb * 4 + lk) ^ (row & 7);
                ah[mf] = *(short8*)&featA[row * 256 + g * 8];
            }
            const int bidx0 = ((kb * 256 + ec) * 4 + lk) * 8;
            const int bidx1 = ((kb * 256 + 128 + ec) * 4 + lk) * 8;
            const short8 bh0 = *(const short8*)&g_w1hi[bidx0];
            const short8 bl0 = *(const short8*)&g_w1lo[bidx0];
            const short8 bh1 = *(const short8*)&g_w1hi[bidx1];
            const short8 bl1 = *(const short8*)&g_w1lo[bidx1];
            #pragma unroll
            for (int mf = 0; mf < 5; ++mf) {
                acc[mf][0] = __builtin_amdgcn_mfma_f32_16x16x32_bf16(ah[mf], bh0, acc[mf][0], 0, 0, 0);
                acc[mf][0] = __builtin_amdgcn_mfma_f32_16x16x32_bf16(ah[mf], bl0, acc[mf][0], 0, 0, 0);
                acc[mf][1] = __builtin_amdgcn_mfma_f32_16x16x32_bf16(ah[mf], bh1, acc[mf][1], 0, 0, 0);
                acc[mf][1] = __builtin_amdgcn_mfma_f32_16x16x32_bf16(ah[mf], bl1, acc[mf][1], 0, 0, 0);
            }
        }
        __syncthreads();   // all GEMM1 A-reads done before featA h overwrite

        // ---- epilogue 1: r,u; uh,u in regs; featA h <- bf16(r*h) ---------
        #pragma unroll
        for (int mf = 0; mf < 5; ++mf) {
            #pragma unroll
            for (int j = 0; j < 4; ++j) {
                const int row = mf * 16 + lk * 4 + j;
                const float r = fsig(acc[mf][0][j]);
                const float u = fsig(acc[mf][1][j]);
                const float h32 = hbuf[row * HID + ec];
                uh[mf][j] = u * h32;
                us[mf][j] = u;
                const int colk = 128 + ec;
                const int g = (colk >> 3) ^ (row & 7);
                featA[row * 256 + g * 8 + (colk & 7)] = (short)f2bf(r * h32);
            }
        }
        __syncthreads();

        // ---- GEMM2: M=80, N=128, K=256; this wave: cols ec ---------------
        f32x4 acc2[5];
        {
            const float bb = sb2[ec];
            #pragma unroll
            for (int mf = 0; mf < 5; ++mf)
                acc2[mf] = (f32x4){bb, bb, bb, bb};
        }
        #pragma unroll
        for (int kb = 0; kb < 8; ++kb) {
            short8 ah[5];
            #pragma unroll
            for (int mf = 0; mf < 5; ++mf) {
                const int row = mf * 16 + lr;
                const int g   = (kb * 4 + lk) ^ (row & 7);
                ah[mf] = *(short8*)&featA[row * 256 + g * 8];
            }
            const int bidx = ((kb * 128 + ec) * 4 + lk) * 8;
            const short8 bh = *(const short8*)&g_w2hi[bidx];
            const short8 bl = *(const short8*)&g_w2lo[bidx];
            #pragma unroll
            for (int mf = 0; mf < 5; ++mf) {
                acc2[mf] = __builtin_amdgcn_mfma_f32_16x16x32_bf16(ah[mf], bh, acc2[mf], 0, 0, 0);
                acc2[mf] = __builtin_amdgcn_mfma_f32_16x16x32_bf16(ah[mf], bl, acc2[mf], 0, 0, 0);
            }
        }
        __syncthreads();   // all GEMM2 A-reads done before featA h overwrite

        // ---- epilogue 2: c = tanh; h_new = u*h + (1-u)*c ------------------
        #pragma unroll
        for (int mf = 0; mf < 5; ++mf) {
            #pragma unroll
            for (int j = 0; j < 4; ++j) {
                const int row = mf * 16 + lk * 4 + j;
                const float c  = tanhf(acc2[mf][j]);
                const float hn = uh[mf][j] + c - us[mf][j] * c;
                if (step < T_STEPS - 1) {
                    hbuf[row * HID + ec] = hn;
                    const int colk = 128 + ec;
                    const int g = (colk >> 3) ^ (row & 7);
                    featA[row * 256 + g * 8 + (colk & 7)] = (short)f2bf(hn);
                } else {
                    hout[(size_t)(n0g + row) * HID + ec] = hn;
                }
            }
        }
        // no barrier needed: next phase0 writes f-region only (disjoint);
        // GEMM1 readers are fenced by the post-phase0 barrier.
    }
}

// ---------------------------------------------------------------------------
extern "C" void kernel_launch(void* const* d_in, const int* in_sizes, int n_in,
                              void* d_out, int out_size, void* d_ws, size_t ws_size,
                              hipStream_t stream) {
    const float* x   = (const float*)d_in[0];
    const void*  ei  = d_in[1];
    // d_in[2] edge_weight: unused by the reference
    const float* W_l = (const float*)d_in[3];
    const float* b_l = (const float*)d_in[4];
    const float* W_r = (const float*)d_in[5];
    const float* b_r = (const float*)d_in[6];
    const float* att = (const float*)d_in[7];
    const float* cb  = (const float*)d_in[8];
    const float* W1  = (const float*)d_in[9];
    const float* b1  = (const float*)d_in[10];
    const float* W2  = (const float*)d_in[11];
    const float* b2  = (const float*)d_in[12];

    float* h = (float*)d_out;
    (void)d_ws; (void)ws_size;

    init_kernel<<<(T_STEPS * N_NODES + 255) / 256, 256, 0, stream>>>(
        x, (const unsigned int*)ei);
    hist_kernel<<<(E_EDGES + 255) / 256, 256, 0, stream>>>(ei);
    scan_kernel<<<1, 1024, 0, stream>>>();
    scatter_kernel<<<(E_EDGES + 255) / 256, 256, 0, stream>>>(ei);
    prep_kernel<<<384, 256, 0, stream>>>(W1, W2, W_l, b_l, W_r, b_r, att);
    edge_all_kernel<<<dim3(157, T_STEPS), 256, 0, stream>>>(W_l, b_l, W_r, b_r, att);
    gru_all_kernel<<<N_NODES / BN, 512, 0, stream>>>(W_l, b_l, cb, b1, b2, h);
}